// Round 11
// baseline (215.818 us; speedup 1.0000x reference)
//
#include <hip/hip_runtime.h>

#define B_PAT 32
#define RTOT 2048
#define NV 32
#define LMAX 1008
#define NTS 16
#define NIN 64    // K-padded feature width (from 34)
#define TLD 72    // feature tile LDS row stride (ushorts)
#define HW 128    // MLP width / hidden
#define LDSP 136  // LDS row stride for MLP bufs (ushorts)
#define NCH 16    // position-chunks per patient
#define CH 63     // positions per chunk
#define ELD 132   // enc LDS stride (floats)
#define RLD 136   // r LDS stride (floats)

typedef __attribute__((ext_vector_type(8))) short short8;
typedef __attribute__((ext_vector_type(4))) float floatx4;

__device__ __forceinline__ ushort f2b(float f) {
  unsigned int x = __float_as_uint(f);
  unsigned int r = (x + 0x7FFFu + ((x >> 16) & 1u)) >> 16;
  return (ushort)r;
}
__device__ __forceinline__ unsigned int pack2(ushort lo, ushort hi) {
  return (unsigned int)lo | ((unsigned int)hi << 16);
}
__device__ __forceinline__ float tscale(int i) {
  return exp2f((float)i * (6.643856189774724f / 15.0f)); // 100^(i/15)
}

// ---------------------------------------------------------------------------
// kP: blocks 0..31 — per-patient prep: row counts + scan -> pbase/lens/rowstart,
// per-row times, q-row -> fp32 GEMV chain -> folded r (bk softmax-invariant),
// zero the per-patient chunk counter. blocks 32..34 — weight conversions.
// ---------------------------------------------------------------------------
__global__ __launch_bounds__(256) void kP(
    const float* __restrict__ times, const int* __restrict__ time_ptr,
    const float* __restrict__ X, const int* __restrict__ M,
    const int* __restrict__ obs_idx,
    const float* __restrict__ W0, const float* __restrict__ b0,
    const float* __restrict__ W1, const float* __restrict__ b1,
    const float* __restrict__ W2, const float* __restrict__ b2,
    const float* __restrict__ Wq, const float* __restrict__ bq,
    const float* __restrict__ Wk,
    int* __restrict__ pbase_g, int* __restrict__ rowstart_g,
    int* __restrict__ lens, float* __restrict__ trow_g,
    ushort* __restrict__ W0p, ushort* __restrict__ W1b, ushort* __restrict__ W2b,
    float* __restrict__ r_all, int* __restrict__ cnt_g)
{
  const int b = blockIdx.x;
  const int t = threadIdx.x;
  if (b >= B_PAT) {
    if (b == B_PAT) {
      for (int i = t; i < HW * NIN; i += 256) {
        int n = i >> 6, k = i & 63;
        W0p[i] = (k < 34) ? f2b(W0[n * 34 + k]) : (ushort)0;
      }
    } else if (b == B_PAT + 1) {
      for (int i = t; i < HW * HW; i += 256) W1b[i] = f2b(W1[i]);
    } else {
      for (int i = t; i < HW * HW; i += 256) W2b[i] = f2b(W2[i]);
    }
    return;
  }
  if (t == 0) cnt_g[b] = 0;   // ws is re-poisoned every call; kP runs before kF
  __shared__ int rs_s, re_s;
  __shared__ int cnt_s[64];
  __shared__ int pbase_s[65];
  __shared__ float tval_s[64];
  __shared__ int qrc[3];
  __shared__ float x_s[64];
  __shared__ float h0[HW], h1[HW], eq[HW], q_s[HW], part[256];
  // find patient row range
  for (int r = t * 8; r < t * 8 + 8; ++r) {
    if (obs_idx[r] == b) {
      if (r == 0 || obs_idx[r - 1] != b) rs_s = r;
      if (r == RTOT - 1 || obs_idx[r + 1] != b) re_s = r + 1;
    }
  }
  __syncthreads();
  const int rs = rs_s, re = re_s;
  const int n = re - rs;  // <= 64
  if (t < 64) {
    int c = 0;
    if (t < n) {
      const int4* mp = (const int4*)(M + (size_t)(rs + t) * NV);
#pragma unroll
      for (int q = 0; q < 8; ++q) {
        int4 m4 = mp[q];
        c += (m4.x != 0) + (m4.y != 0) + (m4.z != 0) + (m4.w != 0);
      }
      int lo = 0, hi = RTOT - 1, r = rs + t;
      while (lo < hi) { int mid = (lo + hi + 1) >> 1; if (time_ptr[mid] <= r) lo = mid; else hi = mid - 1; }
      tval_s[t] = times[lo];
      trow_g[r] = times[lo];
    }
    cnt_s[t] = c;
  }
  __syncthreads();
  if (t < 64) {
    int incl = cnt_s[t];
    for (int off = 1; off < 64; off <<= 1) {
      int v = __shfl_up(incl, off);
      if (t >= off) incl += v;
    }
    pbase_s[t + 1] = incl;
    if (t == 0) pbase_s[0] = 0;
  }
  __syncthreads();
  const int len = pbase_s[64];
  if (t < 65) pbase_g[b * 65 + t] = pbase_s[t];
  if (t == 0) { rowstart_g[b] = rs; lens[b] = len; }
  // q-row location (position LMAX-1)
  if (t == 0) {
    if (LMAX - 1 < len) {
      int lr = 0;
      while (pbase_s[lr + 1] <= LMAX - 1) ++lr;
      int k = (LMAX - 1) - pbase_s[lr], col = 0;
      for (int cc = 0; cc < NV; ++cc)
        if (M[(size_t)(rs + lr) * NV + cc] != 0) { if (k == 0) { col = cc; break; } --k; }
      qrc[0] = lr; qrc[1] = col; qrc[2] = 1;
    } else qrc[2] = 0;
  }
  if (t < 64) x_s[t] = 0.0f;
  __syncthreads();
  if (qrc[2] == 0) {
    if (t >= 16 && t < 32) x_s[t] = 1.0f;  // pad row: sin=0, cos=1, col=0, val=0
  } else {
    int lr = qrc[0], col = qrc[1];
    if (t < 16) {
      float a = tval_s[lr] / tscale(t);
      x_s[t] = sinf(a); x_s[16 + t] = cosf(a);
    }
    if (t == 0) { x_s[32] = (float)col; x_s[33] = X[(size_t)(rs + lr) * NV + col]; }
  }
  __syncthreads();
  if (t < HW) {
    float a = b0[t];
#pragma unroll 2
    for (int k = 0; k < 34; ++k) a += W0[t * 34 + k] * x_s[k];
    h0[t] = fmaxf(a, 0.0f);
  }
  __syncthreads();
  {
    int oo = t & 127, hf = t >> 7;
    float a = 0.f;
    const float* wr = W1 + oo * HW + hf * 64;
#pragma unroll 8
    for (int k = 0; k < 64; ++k) a += wr[k] * h0[hf * 64 + k];
    part[t] = a;
  }
  __syncthreads();
  if (t < HW) h1[t] = fmaxf(part[t] + part[t + 128] + b1[t], 0.0f);
  __syncthreads();
  {
    int oo = t & 127, hf = t >> 7;
    float a = 0.f;
    const float* wr = W2 + oo * HW + hf * 64;
#pragma unroll 8
    for (int k = 0; k < 64; ++k) a += wr[k] * h1[hf * 64 + k];
    part[t] = a;
  }
  __syncthreads();
  if (t < HW) eq[t] = part[t] + part[t + 128] + b2[t];
  __syncthreads();
  {
    int oo = t & 127, hf = t >> 7;
    float a = 0.f;
    const float* wr = Wq + oo * HW + hf * 64;
#pragma unroll 8
    for (int k = 0; k < 64; ++k) a += wr[k] * eq[hf * 64 + k];
    part[t] = a;
  }
  __syncthreads();
  if (t < HW) q_s[t] = part[t] + part[t + 128] + bq[t];
  __syncthreads();
  const float scale = 0.17677669529663687f;
  for (int idx = t; idx < 512; idx += 256) {
    int h = idx >> 7, e = idx & 127;
    float a = 0.f;
#pragma unroll 8
    for (int d = 0; d < 32; ++d) a += Wk[(h * 32 + d) * HW + e] * q_s[h * 32 + d];
    r_all[b * 512 + idx] = a * scale;
  }
}

// ---------------------------------------------------------------------------
// kF: block = (patient, uniform 63-position chunk), 512 threads (8 waves).
// Feature tile in LDS (no pre-zero: garbage rows >= valid are row-contained
// through the MFMA layers and masked at logits/wsum), 3-layer MFMA MLP,
// logits, local softmax, partial weighted sums. Last chunk-block per patient
// (device atomic) runs the online-softmax combine -> out. 512 blocks.
// ---------------------------------------------------------------------------
__global__ __launch_bounds__(512) void kF(
    const int* __restrict__ M, const float* __restrict__ X,
    const int* __restrict__ pbase_g, const int* __restrict__ rowstart_g,
    const int* __restrict__ lens, const float* __restrict__ trow_g,
    const ushort* __restrict__ W0p, const float* __restrict__ b0,
    const ushort* __restrict__ W1b, const float* __restrict__ b1,
    const ushort* __restrict__ W2b, const float* __restrict__ b2,
    const float* __restrict__ r_all, float* __restrict__ partial,
    float2* __restrict__ mxsm, int* __restrict__ cnt_g,
    float* __restrict__ out)
{
  const int bx = blockIdx.x;
  const int b = bx >> 4, c = bx & 15;
  const int t = threadIdx.x;
  const int len = lens[b];
  const int start = c * CH;
  int valid = len - start; if (valid > CH) valid = CH;
  __shared__ ushort tile[64 * TLD];
  __shared__ ushort bufA[64 * LDSP];
  __shared__ ushort bufB[64 * LDSP];
  __shared__ float encs[64 * ELD];
  __shared__ float r_s[4 * RLD];
  __shared__ float lg[4 * 64];
  __shared__ unsigned int umask[64];
  __shared__ float tval[64];
  __shared__ int pbase_s[65];
  __shared__ float inv_ts[NTS];
  __shared__ float mx_s[4], sm_s[4];
  __shared__ int last_s;
  __shared__ float f_s[NCH * 4];
  if (valid > 0) {
    const int rs = rowstart_g[b];
    // P0/P1: r load + row masks + times + pbase + inv_ts (one barrier)
    r_s[(t >> 7) * RLD + (t & 127)] = r_all[b * 512 + t];
    if (t < 64) {
      const int4* mp = (const int4*)(M + (size_t)(rs + t) * NV);
      unsigned int mk = 0;
#pragma unroll
      for (int q8 = 0; q8 < 8; ++q8) {
        int4 m4 = mp[q8];
        mk |= (m4.x != 0 ? 1u : 0u) << (q8 * 4);
        mk |= (m4.y != 0 ? 1u : 0u) << (q8 * 4 + 1);
        mk |= (m4.z != 0 ? 1u : 0u) << (q8 * 4 + 2);
        mk |= (m4.w != 0 ? 1u : 0u) << (q8 * 4 + 3);
      }
      umask[t] = mk;
      tval[t] = trow_g[rs + t];
    } else if (t < 129) {
      pbase_s[t - 64] = pbase_g[b * 65 + (t - 64)];
    } else if (t >= 136 && t < 136 + NTS) {
      inv_ts[t - 136] = 1.0f / tscale(t - 136);
    }
    __syncthreads();
    // P2: feature fill — 8 threads per position; subs 5..7 zero K-pad dwords
    {
      int pos = t >> 3, sub = t & 7;
      if (pos < valid) {
        unsigned int* dst = (unsigned int*)(tile + pos * TLD);
        if (sub < 5) {
          int gpos = start + pos;
          int lo = 0, hi = 63;
          while (lo < hi) { int mid = (lo + hi + 1) >> 1; if (pbase_s[mid] <= gpos) lo = mid; else hi = mid - 1; }
          int lrow = lo;
          int rank = gpos - pbase_s[lrow];
          unsigned int m = umask[lrow];
          for (int i = 0; i < rank; ++i) m &= m - 1;
          int col = (m != 0u) ? __builtin_ctz(m) : 0;
          float tv = tval[lrow];
          if (sub < 2) {            // sin halves
#pragma unroll
            for (int w = 0; w < 4; ++w) {
              int i0 = sub * 8 + 2 * w;
              dst[sub * 4 + w] = pack2(f2b(__sinf(tv * inv_ts[i0])), f2b(__sinf(tv * inv_ts[i0 + 1])));
            }
          } else if (sub < 4) {     // cos halves
#pragma unroll
            for (int w = 0; w < 4; ++w) {
              int i0 = (sub - 2) * 8 + 2 * w;
              dst[8 + (sub - 2) * 4 + w] = pack2(f2b(__cosf(tv * inv_ts[i0])), f2b(__cosf(tv * inv_ts[i0 + 1])));
            }
          } else {                  // col/val
            dst[16] = pack2(f2b((float)col), f2b(X[(size_t)(rs + lrow) * NV + col]));
          }
        } else {                    // zero K-pad dwords 17..31
          int d0 = 17 + (sub - 5) * 5;
#pragma unroll
          for (int w = 0; w < 5; ++w) dst[d0 + w] = 0u;
        }
      }
    }
    __syncthreads();
    const int wv = t >> 6, lane = t & 63;
    const int m16 = lane & 15, quad = lane >> 4;
    const int rg = wv & 3, nh = wv >> 2;      // row group / N-half
    const int rowl = rg * 16 + m16;
    // layer 0: tile[.,64] @ W0p^T (K=64), wave covers 4 nt of its N-half
    {
      const short8* ar = (const short8*)(tile + rowl * TLD);
      short8 a0 = ar[quad];
      short8 a1 = ar[4 + quad];
#pragma unroll
      for (int nt = 0; nt < 4; ++nt) {
        int nn = nh * 64 + nt * 16 + m16;
        const short8* br = (const short8*)(W0p + nn * NIN);
        floatx4 acc = {0.f, 0.f, 0.f, 0.f};
        acc = __builtin_amdgcn_mfma_f32_16x16x32_bf16(a0, br[quad], acc, 0, 0, 0);
        acc = __builtin_amdgcn_mfma_f32_16x16x32_bf16(a1, br[4 + quad], acc, 0, 0, 0);
        float bias = b0[nn];
#pragma unroll
        for (int i = 0; i < 4; ++i) {
          float vv = fmaxf(acc[i] + bias, 0.0f);
          bufA[(rg * 16 + quad * 4 + i) * LDSP + nn] = f2b(vv);
        }
      }
    }
    __syncthreads();
    // layer 1 (K=128)
    {
#pragma unroll
      for (int nt = 0; nt < 4; ++nt) {
        int nn = nh * 64 + nt * 16 + m16;
        floatx4 acc = {0.f, 0.f, 0.f, 0.f};
#pragma unroll
        for (int ks = 0; ks < 4; ++ks) {
          short8 a = *(const short8*)(bufA + rowl * LDSP + ks * 32 + quad * 8);
          short8 bb = *(const short8*)(W1b + nn * HW + ks * 32 + quad * 8);
          acc = __builtin_amdgcn_mfma_f32_16x16x32_bf16(a, bb, acc, 0, 0, 0);
        }
        float bias = b1[nn];
#pragma unroll
        for (int i = 0; i < 4; ++i) {
          float vv = fmaxf(acc[i] + bias, 0.0f);
          bufB[(rg * 16 + quad * 4 + i) * LDSP + nn] = f2b(vv);
        }
      }
    }
    __syncthreads();
    // layer 2 (K=128) -> encs fp32
    {
#pragma unroll
      for (int nt = 0; nt < 4; ++nt) {
        int nn = nh * 64 + nt * 16 + m16;
        floatx4 acc = {0.f, 0.f, 0.f, 0.f};
#pragma unroll
        for (int ks = 0; ks < 4; ++ks) {
          short8 a = *(const short8*)(bufB + rowl * LDSP + ks * 32 + quad * 8);
          short8 bb = *(const short8*)(W2b + nn * HW + ks * 32 + quad * 8);
          acc = __builtin_amdgcn_mfma_f32_16x16x32_bf16(a, bb, acc, 0, 0, 0);
        }
        float bias = b2[nn];
#pragma unroll
        for (int i = 0; i < 4; ++i)
          encs[(rg * 16 + quad * 4 + i) * ELD + nn] = acc[i] + bias;
      }
    }
    __syncthreads();
    // logits: thread -> (m = t>>3, h = t&7 with h<4)
    {
      int m = t >> 3, h = t & 7;
      if (m < valid && h < 4) {
        const float4* ev = (const float4*)(&encs[m * ELD]);
        const float4* rv = (const float4*)(&r_s[h * RLD]);
        float acc = 0.f;
#pragma unroll
        for (int e4 = 0; e4 < 32; ++e4) {
          float4 v = ev[e4], r = rv[e4];
          acc += v.x * r.x + v.y * r.y + v.z * r.z + v.w * r.w;
        }
        lg[h * 64 + m] = acc;
      }
    }
    __syncthreads();
    // local softmax per head (waves 0..3 = heads)
    if (wv < 4) {
      float v = (lane < valid) ? lg[wv * 64 + lane] : -1e30f;
      float mx = v;
#pragma unroll
      for (int o = 32; o >= 1; o >>= 1) mx = fmaxf(mx, __shfl_xor(mx, o));
      float p = (lane < valid) ? __expf(v - mx) : 0.f;
      lg[wv * 64 + lane] = p;
      float sm = p;
#pragma unroll
      for (int o = 32; o >= 1; o >>= 1) sm += __shfl_xor(sm, o);
      if (lane == 0) { mx_s[wv] = mx; sm_s[wv] = sm; }
    }
    __syncthreads();
    // partial weighted sums (unnormalized): 1 output per thread
    {
      int h = t >> 7;
      float acc = 0.f;
      int e = t & 127;
      for (int m = 0; m < valid; ++m)
        acc += lg[h * 64 + m] * encs[m * ELD + e];
      partial[(size_t)bx * 512 + t] = acc;
    }
    if (t < 4) mxsm[bx * 4 + t] = make_float2(mx_s[t], sm_s[t]);
  } else {
    if (t < 4) mxsm[bx * 4 + t] = make_float2(-1e30f, 0.0f);
  }
  // ---- last-block combine (canonical: sync -> fence -> atomic) ----
  __syncthreads();
  __threadfence();
  if (t == 0) last_s = (atomicAdd(&cnt_g[b], 1) == NCH - 1) ? 1 : 0;
  __syncthreads();
  if (last_s) {
    __threadfence();
    if (t < 4) {
      int h = t;
      float2 v[NCH];
      float Mx = -1e30f;
#pragma unroll
      for (int cc = 0; cc < NCH; ++cc) {
        v[cc] = mxsm[(b * NCH + cc) * 4 + h];
        if (v[cc].y > 0.f) Mx = fmaxf(Mx, v[cc].x);
      }
      float S = 0.f;
#pragma unroll
      for (int cc = 0; cc < NCH; ++cc)
        if (v[cc].y > 0.f) S += v[cc].y * __expf(v[cc].x - Mx);
      float invS = 1.0f / S;
#pragma unroll
      for (int cc = 0; cc < NCH; ++cc)
        f_s[cc * 4 + h] = (v[cc].y > 0.f) ? __expf(v[cc].x - Mx) * invS : 0.f;
    }
    __syncthreads();
    {
      int h = t >> 7;
      float acc = 0.f;
#pragma unroll
      for (int cc = 0; cc < NCH; ++cc) {
        float f = f_s[cc * 4 + h];
        if (f > 0.f) acc += partial[((size_t)(b * NCH + cc)) * 512 + t] * f;
      }
      out[b * 512 + t] = acc;
    }
  }
}

extern "C" void kernel_launch(void* const* d_in, const int* in_sizes, int n_in,
                              void* d_out, int out_size, void* d_ws, size_t ws_size,
                              hipStream_t stream) {
  const float* times = (const float*)d_in[0];
  const int* time_ptr = (const int*)d_in[1];
  const float* X = (const float*)d_in[2];
  const int* M = (const int*)d_in[3];
  const int* obs_idx = (const int*)d_in[4];
  const float* W0 = (const float*)d_in[6];
  const float* b0 = (const float*)d_in[7];
  const float* W1 = (const float*)d_in[8];
  const float* b1 = (const float*)d_in[9];
  const float* W2 = (const float*)d_in[10];
  const float* b2 = (const float*)d_in[11];
  const float* Wq = (const float*)d_in[12];
  const float* bq = (const float*)d_in[13];
  const float* Wk = (const float*)d_in[14];
  // d_in[15] (bk) is softmax-invariant for the scores -> dropped.
  float* out = (float*)d_out;

  char* ws = (char*)d_ws;
  size_t off = 0;
  int* pbase_g = (int*)(ws + off); off += (size_t)B_PAT * 65 * 4;     // 8.3 KB
  int* rowstart_g = (int*)(ws + off); off += 256;
  int* lens = (int*)(ws + off); off += 256;
  int* cnt_g = (int*)(ws + off); off += 256;
  float* trow_g = (float*)(ws + off); off += RTOT * 4;                // 8 KB
  ushort* W0p = (ushort*)(ws + off); off += (size_t)HW * NIN * 2;     // 16 KB
  ushort* W1b = (ushort*)(ws + off); off += (size_t)HW * HW * 2;      // 32 KB
  ushort* W2b = (ushort*)(ws + off); off += (size_t)HW * HW * 2;      // 32 KB
  float* r_all = (float*)(ws + off); off += (size_t)B_PAT * 512 * 4;  // 64 KB
  float* partial = (float*)(ws + off); off += (size_t)B_PAT * NCH * 512 * 4; // 1 MB
  float2* mxsm = (float2*)(ws + off); off += (size_t)B_PAT * NCH * 4 * 8;    // 16 KB

  kP<<<B_PAT + 3, 256, 0, stream>>>(times, time_ptr, X, M, obs_idx,
                                    W0, b0, W1, b1, W2, b2, Wq, bq, Wk,
                                    pbase_g, rowstart_g, lens, trow_g,
                                    W0p, W1b, W2b, r_all, cnt_g);
  kF<<<B_PAT * NCH, 512, 0, stream>>>(M, X, pbase_g, rowstart_g, lens, trow_g,
                                      W0p, b0, W1b, b1, W2b, b2, r_all,
                                      partial, mxsm, cnt_g, out);
}

// Round 12
// 140.514 us; speedup vs baseline: 1.5359x; 1.5359x over previous
//
#include <hip/hip_runtime.h>

#define B_PAT 32
#define RTOT 2048
#define NV 32
#define LMAX 1008
#define NTS 16
#define NIN 64    // K-padded feature width (from 34)
#define TLD 72    // feature tile LDS row stride (ushorts)
#define HW 128    // MLP width / hidden
#define LDSP 136  // LDS row stride for MLP bufs (ushorts)
#define NCH 16    // position-chunks per patient
#define CH 63     // positions per chunk
#define ELD 132   // enc LDS stride (floats)
#define RLD 136   // r LDS stride (floats)

typedef __attribute__((ext_vector_type(8))) short short8;
typedef __attribute__((ext_vector_type(4))) float floatx4;

__device__ __forceinline__ ushort f2b(float f) {
  unsigned int x = __float_as_uint(f);
  unsigned int r = (x + 0x7FFFu + ((x >> 16) & 1u)) >> 16;
  return (ushort)r;
}
__device__ __forceinline__ unsigned int pack2(ushort lo, ushort hi) {
  return (unsigned int)lo | ((unsigned int)hi << 16);
}
__device__ __forceinline__ float tscale(int i) {
  return exp2f((float)i * (6.643856189774724f / 15.0f)); // 100^(i/15)
}

// ---------------------------------------------------------------------------
// kP: blocks 0..31 — per-patient prep: row counts + scan -> pbase/lens/rowstart,
// per-row times, q-row -> fp32 GEMV chain -> folded r (bk softmax-invariant).
// blocks 32..34 — weight conversions to bf16 (W0 K-padded).
// ---------------------------------------------------------------------------
__global__ __launch_bounds__(256) void kP(
    const float* __restrict__ times, const int* __restrict__ time_ptr,
    const float* __restrict__ X, const int* __restrict__ M,
    const int* __restrict__ obs_idx,
    const float* __restrict__ W0, const float* __restrict__ b0,
    const float* __restrict__ W1, const float* __restrict__ b1,
    const float* __restrict__ W2, const float* __restrict__ b2,
    const float* __restrict__ Wq, const float* __restrict__ bq,
    const float* __restrict__ Wk,
    int* __restrict__ pbase_g, int* __restrict__ rowstart_g,
    int* __restrict__ lens, float* __restrict__ trow_g,
    ushort* __restrict__ W0p, ushort* __restrict__ W1b, ushort* __restrict__ W2b,
    float* __restrict__ r_all)
{
  const int b = blockIdx.x;
  const int t = threadIdx.x;
  if (b >= B_PAT) {
    if (b == B_PAT) {
      for (int i = t; i < HW * NIN; i += 256) {
        int n = i >> 6, k = i & 63;
        W0p[i] = (k < 34) ? f2b(W0[n * 34 + k]) : (ushort)0;
      }
    } else if (b == B_PAT + 1) {
      for (int i = t; i < HW * HW; i += 256) W1b[i] = f2b(W1[i]);
    } else {
      for (int i = t; i < HW * HW; i += 256) W2b[i] = f2b(W2[i]);
    }
    return;
  }
  __shared__ int rs_s, re_s;
  __shared__ int cnt_s[64];
  __shared__ int pbase_s[65];
  __shared__ float tval_s[64];
  __shared__ int qrc[3];
  __shared__ float x_s[64];
  __shared__ float h0[HW], h1[HW], eq[HW], q_s[HW], part[256];
  // find patient row range
  for (int r = t * 8; r < t * 8 + 8; ++r) {
    if (obs_idx[r] == b) {
      if (r == 0 || obs_idx[r - 1] != b) rs_s = r;
      if (r == RTOT - 1 || obs_idx[r + 1] != b) re_s = r + 1;
    }
  }
  __syncthreads();
  const int rs = rs_s, re = re_s;
  const int n = re - rs;  // <= 64
  if (t < 64) {
    int c = 0;
    if (t < n) {
      const int4* mp = (const int4*)(M + (size_t)(rs + t) * NV);
#pragma unroll
      for (int q = 0; q < 8; ++q) {
        int4 m4 = mp[q];
        c += (m4.x != 0) + (m4.y != 0) + (m4.z != 0) + (m4.w != 0);
      }
      int lo = 0, hi = RTOT - 1, r = rs + t;
      while (lo < hi) { int mid = (lo + hi + 1) >> 1; if (time_ptr[mid] <= r) lo = mid; else hi = mid - 1; }
      tval_s[t] = times[lo];
      trow_g[r] = times[lo];
    }
    cnt_s[t] = c;
  }
  __syncthreads();
  if (t < 64) {
    int incl = cnt_s[t];
    for (int off = 1; off < 64; off <<= 1) {
      int v = __shfl_up(incl, off);
      if (t >= off) incl += v;
    }
    pbase_s[t + 1] = incl;
    if (t == 0) pbase_s[0] = 0;
  }
  __syncthreads();
  const int len = pbase_s[64];
  if (t < 65) pbase_g[b * 65 + t] = pbase_s[t];
  if (t == 0) { rowstart_g[b] = rs; lens[b] = len; }
  // q-row location (position LMAX-1)
  if (t == 0) {
    if (LMAX - 1 < len) {
      int lr = 0;
      while (pbase_s[lr + 1] <= LMAX - 1) ++lr;
      int k = (LMAX - 1) - pbase_s[lr], col = 0;
      for (int cc = 0; cc < NV; ++cc)
        if (M[(size_t)(rs + lr) * NV + cc] != 0) { if (k == 0) { col = cc; break; } --k; }
      qrc[0] = lr; qrc[1] = col; qrc[2] = 1;
    } else qrc[2] = 0;
  }
  if (t < 64) x_s[t] = 0.0f;
  __syncthreads();
  if (qrc[2] == 0) {
    if (t >= 16 && t < 32) x_s[t] = 1.0f;  // pad row: sin=0, cos=1, col=0, val=0
  } else {
    int lr = qrc[0], col = qrc[1];
    if (t < 16) {
      float a = tval_s[lr] / tscale(t);
      x_s[t] = sinf(a); x_s[16 + t] = cosf(a);
    }
    if (t == 0) { x_s[32] = (float)col; x_s[33] = X[(size_t)(rs + lr) * NV + col]; }
  }
  __syncthreads();
  if (t < HW) {
    float a = b0[t];
#pragma unroll 2
    for (int k = 0; k < 34; ++k) a += W0[t * 34 + k] * x_s[k];
    h0[t] = fmaxf(a, 0.0f);
  }
  __syncthreads();
  {
    int oo = t & 127, hf = t >> 7;
    float a = 0.f;
    const float* wr = W1 + oo * HW + hf * 64;
#pragma unroll 8
    for (int k = 0; k < 64; ++k) a += wr[k] * h0[hf * 64 + k];
    part[t] = a;
  }
  __syncthreads();
  if (t < HW) h1[t] = fmaxf(part[t] + part[t + 128] + b1[t], 0.0f);
  __syncthreads();
  {
    int oo = t & 127, hf = t >> 7;
    float a = 0.f;
    const float* wr = W2 + oo * HW + hf * 64;
#pragma unroll 8
    for (int k = 0; k < 64; ++k) a += wr[k] * h1[hf * 64 + k];
    part[t] = a;
  }
  __syncthreads();
  if (t < HW) eq[t] = part[t] + part[t + 128] + b2[t];
  __syncthreads();
  {
    int oo = t & 127, hf = t >> 7;
    float a = 0.f;
    const float* wr = Wq + oo * HW + hf * 64;
#pragma unroll 8
    for (int k = 0; k < 64; ++k) a += wr[k] * eq[hf * 64 + k];
    part[t] = a;
  }
  __syncthreads();
  if (t < HW) q_s[t] = part[t] + part[t + 128] + bq[t];
  __syncthreads();
  const float scale = 0.17677669529663687f;
  for (int idx = t; idx < 512; idx += 256) {
    int h = idx >> 7, e = idx & 127;
    float a = 0.f;
#pragma unroll 8
    for (int d = 0; d < 32; ++d) a += Wk[(h * 32 + d) * HW + e] * q_s[h * 32 + d];
    r_all[b * 512 + idx] = a * scale;
  }
}

// ---------------------------------------------------------------------------
// kF: block = (patient, uniform 63-position chunk), 512 threads (8 waves).
// Feature tile in LDS (no pre-zero: rows >= valid are row-contained through
// the MFMA layers and masked at logits/wsum; K-pad dwords of valid rows are
// zeroed in P2), 3-layer MFMA MLP (fp32 accum) -> encs in LDS -> logits ->
// local softmax -> partial weighted sums. 512 blocks, no device fences.
// ---------------------------------------------------------------------------
__global__ __launch_bounds__(512) void kF(
    const int* __restrict__ M, const float* __restrict__ X,
    const int* __restrict__ pbase_g, const int* __restrict__ rowstart_g,
    const int* __restrict__ lens, const float* __restrict__ trow_g,
    const ushort* __restrict__ W0p, const float* __restrict__ b0,
    const ushort* __restrict__ W1b, const float* __restrict__ b1,
    const ushort* __restrict__ W2b, const float* __restrict__ b2,
    const float* __restrict__ r_all, float* __restrict__ partial,
    float2* __restrict__ mxsm)
{
  const int bx = blockIdx.x;
  const int b = bx >> 4, c = bx & 15;
  const int t = threadIdx.x;
  const int len = lens[b];
  const int start = c * CH;
  int valid = len - start; if (valid > CH) valid = CH;
  if (valid <= 0) {
    if (t < 4) mxsm[bx * 4 + t] = make_float2(-1e30f, 0.0f);
    return;
  }
  __shared__ ushort tile[64 * TLD];
  __shared__ ushort bufA[64 * LDSP];
  __shared__ ushort bufB[64 * LDSP];
  __shared__ float encs[64 * ELD];
  __shared__ float r_s[4 * RLD];
  __shared__ float lg[4 * 64];
  __shared__ unsigned int umask[64];
  __shared__ float tval[64];
  __shared__ int pbase_s[65];
  __shared__ float inv_ts[NTS];
  __shared__ float mx_s[4], sm_s[4];
  const int rs = rowstart_g[b];
  // P0/P1: r load + row masks + times + pbase + inv_ts (one barrier)
  r_s[(t >> 7) * RLD + (t & 127)] = r_all[b * 512 + t];
  if (t < 64) {
    const int4* mp = (const int4*)(M + (size_t)(rs + t) * NV);
    unsigned int mk = 0;
#pragma unroll
    for (int q8 = 0; q8 < 8; ++q8) {
      int4 m4 = mp[q8];
      mk |= (m4.x != 0 ? 1u : 0u) << (q8 * 4);
      mk |= (m4.y != 0 ? 1u : 0u) << (q8 * 4 + 1);
      mk |= (m4.z != 0 ? 1u : 0u) << (q8 * 4 + 2);
      mk |= (m4.w != 0 ? 1u : 0u) << (q8 * 4 + 3);
    }
    umask[t] = mk;
    tval[t] = trow_g[rs + t];
  } else if (t < 129) {
    pbase_s[t - 64] = pbase_g[b * 65 + (t - 64)];
  } else if (t >= 136 && t < 136 + NTS) {
    inv_ts[t - 136] = 1.0f / tscale(t - 136);
  }
  __syncthreads();
  // P2: feature fill — 8 threads per position; subs 5..7 zero K-pad dwords
  {
    int pos = t >> 3, sub = t & 7;
    if (pos < valid) {
      unsigned int* dst = (unsigned int*)(tile + pos * TLD);
      if (sub < 5) {
        int gpos = start + pos;
        int lo = 0, hi = 63;
        while (lo < hi) { int mid = (lo + hi + 1) >> 1; if (pbase_s[mid] <= gpos) lo = mid; else hi = mid - 1; }
        int lrow = lo;
        int rank = gpos - pbase_s[lrow];
        unsigned int m = umask[lrow];
        for (int i = 0; i < rank; ++i) m &= m - 1;
        int col = (m != 0u) ? __builtin_ctz(m) : 0;
        float tv = tval[lrow];
        if (sub < 2) {            // sin halves
#pragma unroll
          for (int w = 0; w < 4; ++w) {
            int i0 = sub * 8 + 2 * w;
            dst[sub * 4 + w] = pack2(f2b(__sinf(tv * inv_ts[i0])), f2b(__sinf(tv * inv_ts[i0 + 1])));
          }
        } else if (sub < 4) {     // cos halves
#pragma unroll
          for (int w = 0; w < 4; ++w) {
            int i0 = (sub - 2) * 8 + 2 * w;
            dst[8 + (sub - 2) * 4 + w] = pack2(f2b(__cosf(tv * inv_ts[i0])), f2b(__cosf(tv * inv_ts[i0 + 1])));
          }
        } else {                  // col/val
          dst[16] = pack2(f2b((float)col), f2b(X[(size_t)(rs + lrow) * NV + col]));
        }
      } else {                    // zero K-pad dwords 17..31
        int d0 = 17 + (sub - 5) * 5;
#pragma unroll
        for (int w = 0; w < 5; ++w) dst[d0 + w] = 0u;
      }
    }
  }
  __syncthreads();
  const int wv = t >> 6, lane = t & 63;
  const int m16 = lane & 15, quad = lane >> 4;
  const int rg = wv & 3, nh = wv >> 2;      // row group / N-half
  const int rowl = rg * 16 + m16;
  // layer 0: tile[.,64] @ W0p^T (K=64), wave covers 4 nt of its N-half
  {
    const short8* ar = (const short8*)(tile + rowl * TLD);
    short8 a0 = ar[quad];
    short8 a1 = ar[4 + quad];
#pragma unroll
    for (int nt = 0; nt < 4; ++nt) {
      int nn = nh * 64 + nt * 16 + m16;
      const short8* br = (const short8*)(W0p + nn * NIN);
      floatx4 acc = {0.f, 0.f, 0.f, 0.f};
      acc = __builtin_amdgcn_mfma_f32_16x16x32_bf16(a0, br[quad], acc, 0, 0, 0);
      acc = __builtin_amdgcn_mfma_f32_16x16x32_bf16(a1, br[4 + quad], acc, 0, 0, 0);
      float bias = b0[nn];
#pragma unroll
      for (int i = 0; i < 4; ++i) {
        float vv = fmaxf(acc[i] + bias, 0.0f);
        bufA[(rg * 16 + quad * 4 + i) * LDSP + nn] = f2b(vv);
      }
    }
  }
  __syncthreads();
  // layer 1 (K=128)
  {
#pragma unroll
    for (int nt = 0; nt < 4; ++nt) {
      int nn = nh * 64 + nt * 16 + m16;
      floatx4 acc = {0.f, 0.f, 0.f, 0.f};
#pragma unroll
      for (int ks = 0; ks < 4; ++ks) {
        short8 a = *(const short8*)(bufA + rowl * LDSP + ks * 32 + quad * 8);
        short8 bb = *(const short8*)(W1b + nn * HW + ks * 32 + quad * 8);
        acc = __builtin_amdgcn_mfma_f32_16x16x32_bf16(a, bb, acc, 0, 0, 0);
      }
      float bias = b1[nn];
#pragma unroll
      for (int i = 0; i < 4; ++i) {
        float vv = fmaxf(acc[i] + bias, 0.0f);
        bufB[(rg * 16 + quad * 4 + i) * LDSP + nn] = f2b(vv);
      }
    }
  }
  __syncthreads();
  // layer 2 (K=128) -> encs fp32
  {
#pragma unroll
    for (int nt = 0; nt < 4; ++nt) {
      int nn = nh * 64 + nt * 16 + m16;
      floatx4 acc = {0.f, 0.f, 0.f, 0.f};
#pragma unroll
      for (int ks = 0; ks < 4; ++ks) {
        short8 a = *(const short8*)(bufB + rowl * LDSP + ks * 32 + quad * 8);
        short8 bb = *(const short8*)(W2b + nn * HW + ks * 32 + quad * 8);
        acc = __builtin_amdgcn_mfma_f32_16x16x32_bf16(a, bb, acc, 0, 0, 0);
      }
      float bias = b2[nn];
#pragma unroll
      for (int i = 0; i < 4; ++i)
        encs[(rg * 16 + quad * 4 + i) * ELD + nn] = acc[i] + bias;
    }
  }
  __syncthreads();
  // logits: thread -> (m = t>>3, h = t&7 with h<4)
  {
    int m = t >> 3, h = t & 7;
    if (m < valid && h < 4) {
      const float4* ev = (const float4*)(&encs[m * ELD]);
      const float4* rv = (const float4*)(&r_s[h * RLD]);
      float acc = 0.f;
#pragma unroll
      for (int e4 = 0; e4 < 32; ++e4) {
        float4 v = ev[e4], r = rv[e4];
        acc += v.x * r.x + v.y * r.y + v.z * r.z + v.w * r.w;
      }
      lg[h * 64 + m] = acc;
    }
  }
  __syncthreads();
  // local softmax per head (waves 0..3 = heads)
  if (wv < 4) {
    float v = (lane < valid) ? lg[wv * 64 + lane] : -1e30f;
    float mx = v;
#pragma unroll
    for (int o = 32; o >= 1; o >>= 1) mx = fmaxf(mx, __shfl_xor(mx, o));
    float p = (lane < valid) ? __expf(v - mx) : 0.f;
    lg[wv * 64 + lane] = p;
    float sm = p;
#pragma unroll
    for (int o = 32; o >= 1; o >>= 1) sm += __shfl_xor(sm, o);
    if (lane == 0) { mx_s[wv] = mx; sm_s[wv] = sm; }
  }
  __syncthreads();
  // partial weighted sums (unnormalized): 1 output per thread
  {
    int h = t >> 7, e = t & 127;
    float acc = 0.f;
    for (int m = 0; m < valid; ++m)
      acc += lg[h * 64 + m] * encs[m * ELD + e];
    partial[(size_t)bx * 512 + t] = acc;
  }
  if (t < 4) mxsm[bx * 4 + t] = make_float2(mx_s[t], sm_s[t]);
}

// ---------------------------------------------------------------------------
// kK: combine 16 chunks with online-softmax rescaling. 32 blocks.
// ---------------------------------------------------------------------------
__global__ __launch_bounds__(256) void kK(
    const float* __restrict__ partial, const float2* __restrict__ mxsm,
    float* __restrict__ out)
{
  const int b = blockIdx.x;
  const int tid = threadIdx.x;
  __shared__ float f_s[NCH * 4];
  if (tid < 4) {
    int h = tid;
    float2 v[NCH];
    float M = -1e30f;
#pragma unroll
    for (int c = 0; c < NCH; ++c) {
      v[c] = mxsm[(b * NCH + c) * 4 + h];
      if (v[c].y > 0.f) M = fmaxf(M, v[c].x);
    }
    float S = 0.f;
#pragma unroll
    for (int c = 0; c < NCH; ++c)
      if (v[c].y > 0.f) S += v[c].y * expf(v[c].x - M);
    float invS = 1.0f / S;
#pragma unroll
    for (int c = 0; c < NCH; ++c)
      f_s[c * 4 + h] = (v[c].y > 0.f) ? expf(v[c].x - M) * invS : 0.f;
  }
  __syncthreads();
  for (int idx = tid; idx < 512; idx += 256) {
    int h = idx >> 7;
    float acc = 0.f;
#pragma unroll
    for (int c = 0; c < NCH; ++c) {
      float f = f_s[c * 4 + h];
      if (f > 0.f) acc += partial[((size_t)(b * NCH + c)) * 512 + idx] * f;
    }
    out[b * 512 + idx] = acc;
  }
}

extern "C" void kernel_launch(void* const* d_in, const int* in_sizes, int n_in,
                              void* d_out, int out_size, void* d_ws, size_t ws_size,
                              hipStream_t stream) {
  const float* times = (const float*)d_in[0];
  const int* time_ptr = (const int*)d_in[1];
  const float* X = (const float*)d_in[2];
  const int* M = (const int*)d_in[3];
  const int* obs_idx = (const int*)d_in[4];
  const float* W0 = (const float*)d_in[6];
  const float* b0 = (const float*)d_in[7];
  const float* W1 = (const float*)d_in[8];
  const float* b1 = (const float*)d_in[9];
  const float* W2 = (const float*)d_in[10];
  const float* b2 = (const float*)d_in[11];
  const float* Wq = (const float*)d_in[12];
  const float* bq = (const float*)d_in[13];
  const float* Wk = (const float*)d_in[14];
  // d_in[15] (bk) is softmax-invariant for the scores -> dropped.
  float* out = (float*)d_out;

  char* ws = (char*)d_ws;
  size_t off = 0;
  int* pbase_g = (int*)(ws + off); off += (size_t)B_PAT * 65 * 4;     // 8.3 KB
  int* rowstart_g = (int*)(ws + off); off += 256;
  int* lens = (int*)(ws + off); off += 256;
  float* trow_g = (float*)(ws + off); off += RTOT * 4;                // 8 KB
  ushort* W0p = (ushort*)(ws + off); off += (size_t)HW * NIN * 2;     // 16 KB
  ushort* W1b = (ushort*)(ws + off); off += (size_t)HW * HW * 2;      // 32 KB
  ushort* W2b = (ushort*)(ws + off); off += (size_t)HW * HW * 2;      // 32 KB
  float* r_all = (float*)(ws + off); off += (size_t)B_PAT * 512 * 4;  // 64 KB
  float* partial = (float*)(ws + off); off += (size_t)B_PAT * NCH * 512 * 4; // 1 MB
  float2* mxsm = (float2*)(ws + off); off += (size_t)B_PAT * NCH * 4 * 8;    // 16 KB

  kP<<<B_PAT + 3, 256, 0, stream>>>(times, time_ptr, X, M, obs_idx,
                                    W0, b0, W1, b1, W2, b2, Wq, bq, Wk,
                                    pbase_g, rowstart_g, lens, trow_g,
                                    W0p, W1b, W2b, r_all);
  kF<<<B_PAT * NCH, 512, 0, stream>>>(M, X, pbase_g, rowstart_g, lens, trow_g,
                                      W0p, b0, W1b, b1, W2b, b2, r_all,
                                      partial, mxsm);
  kK<<<B_PAT, 256, 0, stream>>>(partial, mxsm, out);
}